// Round 2
// baseline (2319.854 us; speedup 1.0000x reference)
//
#include <hip/hip_runtime.h>
#include <hip/hip_bf16.h>
#include <math.h>

#define NHEADS 32
#define HDIM 128
#define POOLW 16
#define DMODEL 1536
#define SPOOL 512
#define HDTOT 4096   // NHEADS*HDIM
#define PEROWS 1024  // 2*SPOOL

// ---------------------------------------------------------------------------
// Kernel 1: pool (mean over 16) + RMSNorm + GELU(exact)
// grid: SPOOL blocks, 256 threads. Writes x_norm and x_gelu (fp32 ws).
// ---------------------------------------------------------------------------
__global__ __launch_bounds__(256) void pool_rms_gelu(
    const float* __restrict__ x, const float* __restrict__ w_rms,
    float* __restrict__ xn, float* __restrict__ xg) {
  int sp = blockIdx.x;
  int tid = threadIdx.x;
  __shared__ float buf[DMODEL];
  __shared__ float red[256];
  const float* xrow = x + (size_t)sp * POOLW * DMODEL;
  float ss = 0.f;
  for (int d = tid; d < DMODEL; d += 256) {
    float s = 0.f;
#pragma unroll
    for (int p = 0; p < POOLW; ++p) s += xrow[p * DMODEL + d];
    s *= (1.0f / POOLW);
    buf[d] = s;
    ss += s * s;
  }
  red[tid] = ss;
  __syncthreads();
  for (int off = 128; off > 0; off >>= 1) {
    if (tid < off) red[tid] += red[tid + off];
    __syncthreads();
  }
  float rms = rsqrtf(red[0] / DMODEL + 1e-6f);
  for (int d = tid; d < DMODEL; d += 256) {
    float v = buf[d] * rms * w_rms[d];
    xn[(size_t)sp * DMODEL + d] = v;
    xg[(size_t)sp * DMODEL + d] = 0.5f * v * (1.0f + erff(v * 0.70710678118654752f));
  }
}

// ---------------------------------------------------------------------------
// Kernel 2: pos_enc[p, j] = sum_f mask[p,f]*(W_pos[f,j] + sign_p*W_pos[32+f,j]) + b_pos[j]
// grid: PEROWS blocks, 256 threads.
// ---------------------------------------------------------------------------
__global__ __launch_bounds__(256) void pos_enc_kernel(
    const float* __restrict__ W_pos, const float* __restrict__ b_pos,
    float* __restrict__ pe) {
  int p = blockIdx.x;   // 0..1023, range_vec = p - 512
  int rv = p - SPOOL;
  float dist = fabsf((float)rv);
  float sgn = (rv > 0) ? 1.f : ((rv < 0) ? -1.f : 0.f);
  __shared__ float m0[NHEADS], m1[NHEADS];
  if (threadIdx.x < NHEADS) {
    int f = threadIdx.x;
    // log_end = log(512 - 32 + 1) = log(481); widths[f] = f + exp(f*log_end/32)
    double ls = log(481.0) / 32.0;
    float e = (float)f * (float)ls;
    float cw = (float)f + expf(e);
    float m = (cw > dist) ? 1.f : 0.f;
    m0[f] = m;
    m1[f] = sgn * m;
  }
  __syncthreads();
  for (int j = threadIdx.x; j < HDTOT; j += 256) {
    float acc = b_pos[j];
#pragma unroll
    for (int f = 0; f < NHEADS; ++f) {
      acc += m0[f] * W_pos[f * HDTOT + j] +
             m1[f] * W_pos[(NHEADS + f) * HDTOT + j];
    }
    pe[(size_t)p * HDTOT + j] = acc;
  }
}

// ---------------------------------------------------------------------------
// Kernel 3: tiled GEMM  C[M][N] = A[M][K] @ B[K][N], all fp32.
// 64x64 tile, BK=16, 256 threads, 4x4 accum per thread.
// ---------------------------------------------------------------------------
#define BM 64
#define BN 64
#define BK 16
#define LDT 68  // padded leading dim to dodge bank conflicts, keeps float4 align

__global__ __launch_bounds__(256) void gemm_f32(
    const float* __restrict__ A, const float* __restrict__ B,
    float* __restrict__ C, int M, int N, int K) {
  __shared__ float As[BK][LDT];
  __shared__ float Bs[BK][LDT];
  int tid = threadIdx.x;
  int tx = tid & 15, ty = tid >> 4;
  int m0 = blockIdx.y * BM, n0 = blockIdx.x * BN;
  int arow = tid >> 2;          // 0..63
  int acol = (tid & 3) * 4;     // 0,4,8,12
  int brow = tid >> 4;          // 0..15
  int bcol = (tid & 15) * 4;    // 0..60
  float acc[4][4] = {};
  for (int k0 = 0; k0 < K; k0 += BK) {
    float4 av = *(const float4*)&A[(size_t)(m0 + arow) * K + k0 + acol];
    As[acol + 0][arow] = av.x;
    As[acol + 1][arow] = av.y;
    As[acol + 2][arow] = av.z;
    As[acol + 3][arow] = av.w;
    float4 bv = *(const float4*)&B[(size_t)(k0 + brow) * N + n0 + bcol];
    Bs[brow][bcol + 0] = bv.x;
    Bs[brow][bcol + 1] = bv.y;
    Bs[brow][bcol + 2] = bv.z;
    Bs[brow][bcol + 3] = bv.w;
    __syncthreads();
#pragma unroll
    for (int kk = 0; kk < BK; ++kk) {
      float4 a4 = *(const float4*)&As[kk][ty * 4];
      float4 b4 = *(const float4*)&Bs[kk][tx * 4];
      float avv[4] = {a4.x, a4.y, a4.z, a4.w};
      float bvv[4] = {b4.x, b4.y, b4.z, b4.w};
#pragma unroll
      for (int i = 0; i < 4; ++i)
#pragma unroll
        for (int j = 0; j < 4; ++j) acc[i][j] += avv[i] * bvv[j];
    }
    __syncthreads();
  }
#pragma unroll
  for (int i = 0; i < 4; ++i) {
    float4 o = {acc[i][0], acc[i][1], acc[i][2], acc[i][3]};
    *(float4*)&C[(size_t)(m0 + ty * 4 + i) * N + n0 + tx * 4] = o;
  }
}

// ---------------------------------------------------------------------------
// Kernel 4: scores  a[q][h][k] = q.k + 0.5*((q+qrb).pe[512+k-q] + (k+krb).pe[512+q-k])
// grid: (SPOOL/256, SPOOL, NHEADS), 256 threads; thread -> one k.
// ---------------------------------------------------------------------------
__global__ __launch_bounds__(256) void score_kernel(
    const float* __restrict__ qb, const float* __restrict__ kb,
    const float* __restrict__ pe,
    const float* __restrict__ qrb, const float* __restrict__ krb,
    float* __restrict__ a) {
  int k = blockIdx.x * 256 + threadIdx.x;
  int q = blockIdx.y;
  int h = blockIdx.z;
  const float4* qrow = (const float4*)(qb + (size_t)q * HDTOT + h * HDIM);
  const float4* krow = (const float4*)(kb + (size_t)k * HDTOT + h * HDIM);
  const float4* peq = (const float4*)(pe + (size_t)(SPOOL + k - q) * HDTOT + h * HDIM);
  const float4* pek = (const float4*)(pe + (size_t)(SPOOL + q - k) * HDTOT + h * HDIM);
  const float4* qrbp = (const float4*)(qrb + h * HDIM);
  const float4* krbp = (const float4*)(krb + h * HDIM);
  float dqk = 0.f, dq = 0.f, dk = 0.f;
#pragma unroll 8
  for (int c4 = 0; c4 < HDIM / 4; ++c4) {
    float4 qv = qrow[c4];
    float4 kv = krow[c4];
    float4 pq = peq[c4];
    float4 pk = pek[c4];
    float4 qr = qrbp[c4];
    float4 kr = krbp[c4];
    float qb0 = qv.x + qr.x;
    float qb1 = qv.y + qr.y;
    float qb2 = qv.z + qr.z;
    float qb3 = qv.w + qr.w;
    float kb0 = kv.x + kr.x;
    float kb1 = kv.y + kr.y;
    float kb2 = kv.z + kr.z;
    float kb3 = kv.w + kr.w;
    dqk += qv.x * kv.x + qv.y * kv.y + qv.z * kv.z + qv.w * kv.w;
    dq += qb0 * pq.x + qb1 * pq.y + qb2 * pq.z + qb3 * pq.w;
    dk += kb0 * pk.x + kb1 * pk.y + kb2 * pk.z + kb3 * pk.w;
  }
  a[((size_t)q * NHEADS + h) * SPOOL + k] = dqk + 0.5f * (dq + dk);
}

// ---------------------------------------------------------------------------
// Kernel 5: pair_act[q][k][c] = sum_h a[q][h][k]*W_pair[h][c] + b_pair[c] + yq[q][c] + yk[k][c]
// grid: (SPOOL/2, SPOOL), 256 threads; (c, one of 2 k) per thread. Output fp32.
// ---------------------------------------------------------------------------
__global__ __launch_bounds__(256) void pair_kernel(
    const float* __restrict__ a, const float* __restrict__ W_pair,
    const float* __restrict__ b_pair, const float* __restrict__ yq,
    const float* __restrict__ yk, float* __restrict__ out) {
  int tid = threadIdx.x;
  int c = tid & 127;
  int kk = tid >> 7;
  int k = blockIdx.x * 2 + kk;
  int q = blockIdx.y;
  float sum = b_pair[c] + yq[(size_t)q * HDIM + c] + yk[(size_t)k * HDIM + c];
  const float* ap = a + (size_t)q * NHEADS * SPOOL + k;
#pragma unroll
  for (int h = 0; h < NHEADS; ++h) {
    sum += ap[h * SPOOL] * W_pair[h * HDIM + c];
  }
  out[((size_t)q * SPOOL + k) * HDIM + c] = sum;
}

// ---------------------------------------------------------------------------
extern "C" void kernel_launch(void* const* d_in, const int* in_sizes, int n_in,
                              void* d_out, int out_size, void* d_ws, size_t ws_size,
                              hipStream_t stream) {
  const float* x      = (const float*)d_in[0];
  const float* w_rms  = (const float*)d_in[1];
  const float* W_q    = (const float*)d_in[2];
  const float* W_k    = (const float*)d_in[3];
  const float* W_pos  = (const float*)d_in[4];
  const float* b_pos  = (const float*)d_in[5];
  const float* qrb    = (const float*)d_in[6];
  const float* krb    = (const float*)d_in[7];
  const float* W_yq   = (const float*)d_in[8];
  const float* W_yk   = (const float*)d_in[9];
  const float* W_pair = (const float*)d_in[10];
  const float* b_pair = (const float*)d_in[11];
  float* out = (float*)d_out;

  // fp32 workspace layout (total ~73.9 MB)
  float* ws = (float*)d_ws;
  float* xn = ws;                          // 512*1536
  float* xg = xn + SPOOL * DMODEL;         // 512*1536
  float* q  = xg + SPOOL * DMODEL;         // 512*4096
  float* k  = q + SPOOL * HDTOT;           // 512*4096
  float* pe = k + SPOOL * HDTOT;           // 1024*4096
  float* yq = pe + (size_t)PEROWS * HDTOT; // 512*128
  float* yk = yq + SPOOL * HDIM;           // 512*128
  float* a  = yk + SPOOL * HDIM;           // 512*32*512

  pool_rms_gelu<<<SPOOL, 256, 0, stream>>>(x, w_rms, xn, xg);
  pos_enc_kernel<<<PEROWS, 256, 0, stream>>>(W_pos, b_pos, pe);

  dim3 g1(HDTOT / BN, SPOOL / BM);
  gemm_f32<<<g1, 256, 0, stream>>>(xn, W_q, q, SPOOL, HDTOT, DMODEL);
  gemm_f32<<<g1, 256, 0, stream>>>(xn, W_k, k, SPOOL, HDTOT, DMODEL);

  dim3 g2(HDIM / BN, SPOOL / BM);
  gemm_f32<<<g2, 256, 0, stream>>>(xg, W_yq, yq, SPOOL, HDIM, DMODEL);
  gemm_f32<<<g2, 256, 0, stream>>>(xg, W_yk, yk, SPOOL, HDIM, DMODEL);

  dim3 g3(SPOOL / 256, SPOOL, NHEADS);
  score_kernel<<<g3, 256, 0, stream>>>(q, k, pe, qrb, krb, a);

  dim3 g4(SPOOL / 2, SPOOL);
  pair_kernel<<<g4, 256, 0, stream>>>(a, W_pair, b_pair, yq, yk, out);
}

// Round 3
// 723.868 us; speedup vs baseline: 3.2048x; 3.2048x over previous
//
#include <hip/hip_runtime.h>
#include <hip/hip_bf16.h>
#include <math.h>
#include <stdint.h>

#define NHEADS 32
#define HDIM 128
#define POOLW 16
#define DMODEL 1536
#define SPOOL 512
#define HDTOT 4096   // NHEADS*HDIM
#define PEROWS 1024  // 2*SPOOL

typedef __hip_bfloat16 bf16;
typedef short short8 __attribute__((ext_vector_type(8)));
typedef float f32x4 __attribute__((ext_vector_type(4)));

__device__ __forceinline__ float b2f(const bf16 v) { return __bfloat162float(v); }
__device__ __forceinline__ bf16 f2b(float v) { return __float2bfloat16(v); }

__device__ __forceinline__ void gload_lds16(const void* g, void* l) {
  const __attribute__((address_space(1))) uint32_t* gp =
      (const __attribute__((address_space(1))) uint32_t*)(uintptr_t)g;
  __attribute__((address_space(3))) uint32_t* lp =
      (__attribute__((address_space(3))) uint32_t*)(uintptr_t)l;
  __builtin_amdgcn_global_load_lds(gp, lp, 16, 0, 0);
}

// ===========================================================================
// NEW PATH (bf16 MFMA)
// ===========================================================================

// K1: pool + RMSNorm + GELU -> bf16 xn, xg
__global__ __launch_bounds__(256) void pool_rms_gelu_bf(
    const float* __restrict__ x, const float* __restrict__ w_rms,
    bf16* __restrict__ xn, bf16* __restrict__ xg) {
  int sp = blockIdx.x;
  int tid = threadIdx.x;
  __shared__ float buf[DMODEL];
  __shared__ float red[256];
  const float* xrow = x + (size_t)sp * POOLW * DMODEL;
  float ss = 0.f;
  for (int d = tid; d < DMODEL; d += 256) {
    float s = 0.f;
#pragma unroll
    for (int p = 0; p < POOLW; ++p) s += xrow[p * DMODEL + d];
    s *= (1.0f / POOLW);
    buf[d] = s;
    ss += s * s;
  }
  red[tid] = ss;
  __syncthreads();
  for (int off = 128; off > 0; off >>= 1) {
    if (tid < off) red[tid] += red[tid + off];
    __syncthreads();
  }
  float rms = rsqrtf(red[0] / DMODEL + 1e-6f);
  for (int d = tid; d < DMODEL; d += 256) {
    float v = buf[d] * rms * w_rms[d];
    xn[(size_t)sp * DMODEL + d] = f2b(v);
    xg[(size_t)sp * DMODEL + d] = f2b(0.5f * v * (1.0f + erff(v * 0.70710678118654752f)));
  }
}

// K2: pos_enc -> bf16 pe[1024][4096]
__global__ __launch_bounds__(256) void pos_enc_bf(
    const float* __restrict__ W_pos, const float* __restrict__ b_pos,
    bf16* __restrict__ pe) {
  int p = blockIdx.x;
  int rv = p - SPOOL;
  float dist = fabsf((float)rv);
  float sgn = (rv > 0) ? 1.f : ((rv < 0) ? -1.f : 0.f);
  __shared__ float m0[NHEADS], m1[NHEADS];
  if (threadIdx.x < NHEADS) {
    int f = threadIdx.x;
    double ls = log(481.0) / 32.0;  // log(512-32+1)/32
    float cw = (float)f + expf((float)f * (float)ls);
    float m = (cw > dist) ? 1.f : 0.f;
    m0[f] = m;
    m1[f] = sgn * m;
  }
  __syncthreads();
  for (int j = threadIdx.x; j < HDTOT; j += 256) {
    float acc = b_pos[j];
#pragma unroll
    for (int f = 0; f < NHEADS; ++f) {
      acc += m0[f] * W_pos[f * HDTOT + j] + m1[f] * W_pos[(NHEADS + f) * HDTOT + j];
    }
    pe[(size_t)p * HDTOT + j] = f2b(acc);
  }
}

// K3: transpose + cast  in[R][C] fp32 -> out[C][R] bf16
__global__ __launch_bounds__(256) void transpose_cast(
    const float* __restrict__ in, bf16* __restrict__ out, int R, int C) {
  __shared__ float tile[32][33];
  int c0 = blockIdx.x * 32, r0 = blockIdx.y * 32;
  int tx = threadIdx.x & 31, ty = threadIdx.x >> 5;  // ty 0..7
  for (int i = ty; i < 32; i += 8) tile[i][tx] = in[(size_t)(r0 + i) * C + c0 + tx];
  __syncthreads();
  for (int i = ty; i < 32; i += 8) out[(size_t)(c0 + i) * R + r0 + tx] = f2b(tile[tx][i]);
}

// K4: bf16 MFMA GEMM:  C[M][N] = A[M][K] @ BT[N][K]^T  (both K-contiguous)
// 128x64 tile, BK=32, 256 threads (4 waves). Verified 16x16x32_bf16 layouts:
//   a_frag[j] = A[m = lane&15][k = (lane>>4)*8 + j]
//   b_frag[j] = B^T[n = lane&15][k = (lane>>4)*8 + j]
//   d[reg]    = D[row = (lane>>4)*4 + reg][col = lane&15]
// LDS octet XOR-swizzle (o ^ (row&3)) to spread ds_read_b128 banks.
__global__ __launch_bounds__(256) void gemm_mfma(
    const bf16* __restrict__ A, int lda, long long batchA,
    const bf16* __restrict__ BT, int ldb, long long batchB,
    float* __restrict__ Cf, bf16* __restrict__ Cb1, bf16* __restrict__ Cb2,
    const float* __restrict__ bias, int ldc, long long batchC,
    int M, int N, int K) {
  __shared__ short Asub[128][32];
  __shared__ short Bsub[64][32];
  const int t = threadIdx.x;
  const int lane = t & 63;
  const int w = t >> 6;
  const int m0 = blockIdx.y * 128, n0 = blockIdx.x * 64;
  const int wm = (w >> 1) * 64, wn = (w & 1) * 32;
  const bf16* Ag = A + (size_t)blockIdx.z * batchA;
  const bf16* Bg = BT + (size_t)blockIdx.z * batchB;

  // staging indices (chunk = 8 bf16 = 16B); thread t stages A-chunks t, t+256 and B-chunk t
  const int ar0 = t >> 2;               // A row for chunk t (0..63)
  const int as0 = t & 3;                // stored octet
  const int ao0 = as0 ^ (ar0 & 3);      // source octet (same for row+64)
  char* AsubB = (char*)&Asub[0][0];
  char* BsubB = (char*)&Bsub[0][0];
  char* ldsA0 = AsubB + w * 1024;
  char* ldsA1 = AsubB + 4096 + w * 1024;
  char* ldsB0 = BsubB + w * 1024;

  const int quad = lane >> 4, mr = lane & 15;
  f32x4 acc[4][2];
#pragma unroll
  for (int mi = 0; mi < 4; ++mi)
#pragma unroll
    for (int ni = 0; ni < 2; ++ni) acc[mi][ni] = (f32x4){0.f, 0.f, 0.f, 0.f};

  for (int k0 = 0; k0 < K; k0 += 32) {
    gload_lds16(Ag + (size_t)(m0 + ar0) * lda + k0 + ao0 * 8, ldsA0);
    gload_lds16(Ag + (size_t)(m0 + 64 + ar0) * lda + k0 + ao0 * 8, ldsA1);
    gload_lds16(Bg + (size_t)(n0 + ar0) * ldb + k0 + ao0 * 8, ldsB0);
    __syncthreads();
    short8 af[4];
#pragma unroll
    for (int mi = 0; mi < 4; ++mi) {
      int r = wm + mi * 16 + mr;
      af[mi] = *(const short8*)&Asub[r][(quad ^ (r & 3)) * 8];
    }
    short8 bfr[2];
#pragma unroll
    for (int ni = 0; ni < 2; ++ni) {
      int r = wn + ni * 16 + mr;
      bfr[ni] = *(const short8*)&Bsub[r][(quad ^ (r & 3)) * 8];
    }
#pragma unroll
    for (int mi = 0; mi < 4; ++mi)
#pragma unroll
      for (int ni = 0; ni < 2; ++ni)
        acc[mi][ni] = __builtin_amdgcn_mfma_f32_16x16x32_bf16(af[mi], bfr[ni], acc[mi][ni], 0, 0, 0);
    __syncthreads();
  }

  size_t cbase = (size_t)blockIdx.z * batchC;
#pragma unroll
  for (int mi = 0; mi < 4; ++mi) {
#pragma unroll
    for (int ni = 0; ni < 2; ++ni) {
#pragma unroll
      for (int r = 0; r < 4; ++r) {
        int gm = m0 + wm + mi * 16 + quad * 4 + r;
        int gn = n0 + wn + ni * 16 + mr;
        float v = acc[mi][ni][r];
        size_t idx = cbase + (size_t)gm * ldc + gn;
        if (Cf) Cf[idx] = v;
        if (Cb1) Cb1[idx] = f2b(v);
        if (Cb2) Cb2[idx] = f2b(v + bias[gn]);
      }
    }
  }
}

// K5: assembly + pair projection
// out[q,k,c] = sum_h (S[h,q,k] + 0.5*(Gq[h,q,512+k-q] + Gk[h,k,512+q-k])) * W_pair[h,c]
//              + b_pair[c] + yqk[q][c] + yqk[k][128+c]
__global__ __launch_bounds__(256) void assembly_pair(
    const bf16* __restrict__ S, const bf16* __restrict__ Gq, const bf16* __restrict__ Gk,
    const float* __restrict__ yqk, const float* __restrict__ W_pair,
    const float* __restrict__ b_pair, float* __restrict__ out) {
  int q = blockIdx.y;
  int k0 = blockIdx.x * 2;
  __shared__ float sh_a[2][32];
  int t = threadIdx.x;
  if (t < 64) {
    int h = t & 31, kk = t >> 5;
    int k = k0 + kk;
    float s = b2f(S[((size_t)h * SPOOL + q) * SPOOL + k]);
    float gq = b2f(Gq[((size_t)h * SPOOL + q) * PEROWS + (SPOOL + k - q)]);
    float gk = b2f(Gk[((size_t)h * SPOOL + k) * PEROWS + (SPOOL + q - k)]);
    sh_a[kk][h] = s + 0.5f * (gq + gk);
  }
  __syncthreads();
  int c = t & 127, kk = t >> 7;
  int k = k0 + kk;
  float sum = b_pair[c] + yqk[(size_t)q * 256 + c] + yqk[(size_t)k * 256 + 128 + c];
#pragma unroll
  for (int h = 0; h < NHEADS; ++h) sum += sh_a[kk][h] * W_pair[h * HDIM + c];
  out[((size_t)q * SPOOL + k) * HDIM + c] = sum;
}

// ===========================================================================
// FALLBACK PATH (round-2 fp32, proven; used only if ws_size too small)
// ===========================================================================

__global__ __launch_bounds__(256) void pool_rms_gelu_f32(
    const float* __restrict__ x, const float* __restrict__ w_rms,
    float* __restrict__ xn, float* __restrict__ xg) {
  int sp = blockIdx.x;
  int tid = threadIdx.x;
  __shared__ float buf[DMODEL];
  __shared__ float red[256];
  const float* xrow = x + (size_t)sp * POOLW * DMODEL;
  float ss = 0.f;
  for (int d = tid; d < DMODEL; d += 256) {
    float s = 0.f;
#pragma unroll
    for (int p = 0; p < POOLW; ++p) s += xrow[p * DMODEL + d];
    s *= (1.0f / POOLW);
    buf[d] = s;
    ss += s * s;
  }
  red[tid] = ss;
  __syncthreads();
  for (int off = 128; off > 0; off >>= 1) {
    if (tid < off) red[tid] += red[tid + off];
    __syncthreads();
  }
  float rms = rsqrtf(red[0] / DMODEL + 1e-6f);
  for (int d = tid; d < DMODEL; d += 256) {
    float v = buf[d] * rms * w_rms[d];
    xn[(size_t)sp * DMODEL + d] = v;
    xg[(size_t)sp * DMODEL + d] = 0.5f * v * (1.0f + erff(v * 0.70710678118654752f));
  }
}

__global__ __launch_bounds__(256) void pos_enc_f32(
    const float* __restrict__ W_pos, const float* __restrict__ b_pos,
    float* __restrict__ pe) {
  int p = blockIdx.x;
  int rv = p - SPOOL;
  float dist = fabsf((float)rv);
  float sgn = (rv > 0) ? 1.f : ((rv < 0) ? -1.f : 0.f);
  __shared__ float m0[NHEADS], m1[NHEADS];
  if (threadIdx.x < NHEADS) {
    int f = threadIdx.x;
    double ls = log(481.0) / 32.0;
    float cw = (float)f + expf((float)f * (float)ls);
    float m = (cw > dist) ? 1.f : 0.f;
    m0[f] = m;
    m1[f] = sgn * m;
  }
  __syncthreads();
  for (int j = threadIdx.x; j < HDTOT; j += 256) {
    float acc = b_pos[j];
#pragma unroll
    for (int f = 0; f < NHEADS; ++f) {
      acc += m0[f] * W_pos[f * HDTOT + j] + m1[f] * W_pos[(NHEADS + f) * HDTOT + j];
    }
    pe[(size_t)p * HDTOT + j] = acc;
  }
}

#define BM 64
#define BN 64
#define BK 16
#define LDT 68

__global__ __launch_bounds__(256) void gemm_f32(
    const float* __restrict__ A, const float* __restrict__ B,
    float* __restrict__ C, int M, int N, int K) {
  __shared__ float As[BK][LDT];
  __shared__ float Bs[BK][LDT];
  int tid = threadIdx.x;
  int tx = tid & 15, ty = tid >> 4;
  int m0 = blockIdx.y * BM, n0 = blockIdx.x * BN;
  int arow = tid >> 2;
  int acol = (tid & 3) * 4;
  int brow = tid >> 4;
  int bcol = (tid & 15) * 4;
  float acc[4][4] = {};
  for (int k0 = 0; k0 < K; k0 += BK) {
    float4 av = *(const float4*)&A[(size_t)(m0 + arow) * K + k0 + acol];
    As[acol + 0][arow] = av.x;
    As[acol + 1][arow] = av.y;
    As[acol + 2][arow] = av.z;
    As[acol + 3][arow] = av.w;
    float4 bv = *(const float4*)&B[(size_t)(k0 + brow) * N + n0 + bcol];
    Bs[brow][bcol + 0] = bv.x;
    Bs[brow][bcol + 1] = bv.y;
    Bs[brow][bcol + 2] = bv.z;
    Bs[brow][bcol + 3] = bv.w;
    __syncthreads();
#pragma unroll
    for (int kk = 0; kk < BK; ++kk) {
      float4 a4 = *(const float4*)&As[kk][ty * 4];
      float4 b4 = *(const float4*)&Bs[kk][tx * 4];
      float avv[4] = {a4.x, a4.y, a4.z, a4.w};
      float bvv[4] = {b4.x, b4.y, b4.z, b4.w};
#pragma unroll
      for (int i = 0; i < 4; ++i)
#pragma unroll
        for (int j = 0; j < 4; ++j) acc[i][j] += avv[i] * bvv[j];
    }
    __syncthreads();
  }
#pragma unroll
  for (int i = 0; i < 4; ++i) {
    float4 o = {acc[i][0], acc[i][1], acc[i][2], acc[i][3]};
    *(float4*)&C[(size_t)(m0 + ty * 4 + i) * N + n0 + tx * 4] = o;
  }
}

__global__ __launch_bounds__(256) void score_kernel(
    const float* __restrict__ qb, const float* __restrict__ kb,
    const float* __restrict__ pe,
    const float* __restrict__ qrb, const float* __restrict__ krb,
    float* __restrict__ a) {
  int k = blockIdx.x * 256 + threadIdx.x;
  int q = blockIdx.y;
  int h = blockIdx.z;
  const float4* qrow = (const float4*)(qb + (size_t)q * HDTOT + h * HDIM);
  const float4* krow = (const float4*)(kb + (size_t)k * HDTOT + h * HDIM);
  const float4* peq = (const float4*)(pe + (size_t)(SPOOL + k - q) * HDTOT + h * HDIM);
  const float4* pek = (const float4*)(pe + (size_t)(SPOOL + q - k) * HDTOT + h * HDIM);
  const float4* qrbp = (const float4*)(qrb + h * HDIM);
  const float4* krbp = (const float4*)(krb + h * HDIM);
  float dqk = 0.f, dq = 0.f, dk = 0.f;
#pragma unroll 8
  for (int c4 = 0; c4 < HDIM / 4; ++c4) {
    float4 qv = qrow[c4];
    float4 kv = krow[c4];
    float4 pq = peq[c4];
    float4 pk = pek[c4];
    float4 qr = qrbp[c4];
    float4 kr = krbp[c4];
    dqk += qv.x * kv.x + qv.y * kv.y + qv.z * kv.z + qv.w * kv.w;
    dq += (qv.x + qr.x) * pq.x + (qv.y + qr.y) * pq.y + (qv.z + qr.z) * pq.z + (qv.w + qr.w) * pq.w;
    dk += (kv.x + kr.x) * pk.x + (kv.y + kr.y) * pk.y + (kv.z + kr.z) * pk.z + (kv.w + kr.w) * pk.w;
  }
  a[((size_t)q * NHEADS + h) * SPOOL + k] = dqk + 0.5f * (dq + dk);
}

__global__ __launch_bounds__(256) void pair_kernel(
    const float* __restrict__ a, const float* __restrict__ W_pair,
    const float* __restrict__ b_pair, const float* __restrict__ yq,
    const float* __restrict__ yk, float* __restrict__ out) {
  int tid = threadIdx.x;
  int c = tid & 127;
  int kk = tid >> 7;
  int k = blockIdx.x * 2 + kk;
  int q = blockIdx.y;
  float sum = b_pair[c] + yq[(size_t)q * HDIM + c] + yk[(size_t)k * HDIM + c];
  const float* ap = a + (size_t)q * NHEADS * SPOOL + k;
#pragma unroll
  for (int h = 0; h < NHEADS; ++h) sum += ap[h * SPOOL] * W_pair[h * HDIM + c];
  out[((size_t)q * SPOOL + k) * HDIM + c] = sum;
}

// ===========================================================================
extern "C" void kernel_launch(void* const* d_in, const int* in_sizes, int n_in,
                              void* d_out, int out_size, void* d_ws, size_t ws_size,
                              hipStream_t stream) {
  const float* x      = (const float*)d_in[0];
  const float* w_rms  = (const float*)d_in[1];
  const float* W_q    = (const float*)d_in[2];
  const float* W_k    = (const float*)d_in[3];
  const float* W_pos  = (const float*)d_in[4];
  const float* b_pos  = (const float*)d_in[5];
  const float* qrb    = (const float*)d_in[6];
  const float* krb    = (const float*)d_in[7];
  const float* W_yq   = (const float*)d_in[8];
  const float* W_yk   = (const float*)d_in[9];
  const float* W_pair = (const float*)d_in[10];
  const float* b_pair = (const float*)d_in[11];
  float* out = (float*)d_out;

  // ---- new-path workspace layout ----
  char* w = (char*)d_ws;
  bf16* xn_bf = (bf16*)w; w += (size_t)SPOOL * DMODEL * 2;
  bf16* xg_bf = (bf16*)w; w += (size_t)SPOOL * DMODEL * 2;
  bf16* pe    = (bf16*)w; w += (size_t)PEROWS * HDTOT * 2;
  bf16* Qp    = (bf16*)w; w += (size_t)SPOOL * HDTOT * 2;
  bf16* Qb    = (bf16*)w; w += (size_t)SPOOL * HDTOT * 2;
  bf16* Kp    = (bf16*)w; w += (size_t)SPOOL * HDTOT * 2;
  bf16* Kb    = (bf16*)w; w += (size_t)SPOOL * HDTOT * 2;
  float* yqk  = (float*)w; w += (size_t)SPOOL * 256 * 4;
  bf16* S     = (bf16*)w; w += (size_t)NHEADS * SPOOL * SPOOL * 2;
  // union region: {WqT, WkT, yqkT} (dead after projections) then {Gq, Gk}
  char* uni = w;
  bf16* WqT  = (bf16*)uni;
  bf16* WkT  = (bf16*)(uni + (size_t)HDTOT * DMODEL * 2);
  bf16* yqkT = (bf16*)(uni + 2 * (size_t)HDTOT * DMODEL * 2);
  bf16* Gq   = (bf16*)uni;
  bf16* Gk   = (bf16*)(uni + (size_t)NHEADS * SPOOL * PEROWS * 2);
  size_t need = (size_t)(uni - (char*)d_ws) + 2 * (size_t)NHEADS * SPOOL * PEROWS * 2;

  if (ws_size >= need) {
    // ======== MFMA path ========
    pool_rms_gelu_bf<<<SPOOL, 256, 0, stream>>>(x, w_rms, xn_bf, xg_bf);
    pos_enc_bf<<<PEROWS, 256, 0, stream>>>(W_pos, b_pos, pe);
    transpose_cast<<<dim3(HDTOT / 32, DMODEL / 32), 256, 0, stream>>>(W_q, WqT, DMODEL, HDTOT);
    transpose_cast<<<dim3(HDTOT / 32, DMODEL / 32), 256, 0, stream>>>(W_k, WkT, DMODEL, HDTOT);
    transpose_cast<<<dim3(HDIM / 32, DMODEL / 32), 256, 0, stream>>>(W_yq, yqkT, DMODEL, HDIM);
    transpose_cast<<<dim3(HDIM / 32, DMODEL / 32), 256, 0, stream>>>(W_yk, yqkT + (size_t)HDIM * DMODEL, DMODEL, HDIM);

    // Q/K projections: M=512, N=4096, K=1536; dual bf16 outputs (plain, +bias)
    gemm_mfma<<<dim3(HDTOT / 64, SPOOL / 128, 1), 256, 0, stream>>>(
        xn_bf, DMODEL, 0, WqT, DMODEL, 0,
        nullptr, Qp, Qb, qrb, HDTOT, 0, SPOOL, HDTOT, DMODEL);
    gemm_mfma<<<dim3(HDTOT / 64, SPOOL / 128, 1), 256, 0, stream>>>(
        xn_bf, DMODEL, 0, WkT, DMODEL, 0,
        nullptr, Kp, Kb, krb, HDTOT, 0, SPOOL, HDTOT, DMODEL);
    // yq|yk: M=512, N=256, K=1536, fp32 out
    gemm_mfma<<<dim3(256 / 64, SPOOL / 128, 1), 256, 0, stream>>>(
        xg_bf, DMODEL, 0, yqkT, DMODEL, 0,
        yqk, nullptr, nullptr, nullptr, 256, 0, SPOOL, 256, DMODEL);
    // S[h] = Q_h @ K_h^T: batched, M=N=512, K=128
    gemm_mfma<<<dim3(SPOOL / 64, SPOOL / 128, NHEADS), 256, 0, stream>>>(
        Qp, HDTOT, HDIM, Kp, HDTOT, HDIM,
        nullptr, S, nullptr, nullptr, SPOOL, (long long)SPOOL * SPOOL, SPOOL, SPOOL, HDIM);
    // Gq[h] = (Q+qrb)_h @ pe_h^T: M=512, N=1024, K=128
    gemm_mfma<<<dim3(PEROWS / 64, SPOOL / 128, NHEADS), 256, 0, stream>>>(
        Qb, HDTOT, HDIM, pe, HDTOT, HDIM,
        nullptr, Gq, nullptr, nullptr, PEROWS, (long long)SPOOL * PEROWS, SPOOL, PEROWS, HDIM);
    gemm_mfma<<<dim3(PEROWS / 64, SPOOL / 128, NHEADS), 256, 0, stream>>>(
        Kb, HDTOT, HDIM, pe, HDTOT, HDIM,
        nullptr, Gk, nullptr, nullptr, PEROWS, (long long)SPOOL * PEROWS, SPOOL, PEROWS, HDIM);

    assembly_pair<<<dim3(SPOOL / 2, SPOOL), 256, 0, stream>>>(
        S, Gq, Gk, yqk, W_pair, b_pair, out);
  } else {
    // ======== fallback fp32 path (round-2, proven at 74 MB) ========
    float* ws = (float*)d_ws;
    float* xn = ws;
    float* xg = xn + SPOOL * DMODEL;
    float* q  = xg + SPOOL * DMODEL;
    float* k  = q + SPOOL * HDTOT;
    float* pef = k + SPOOL * HDTOT;
    float* yq = pef + (size_t)PEROWS * HDTOT;
    float* yk = yq + SPOOL * HDIM;
    float* a  = yk + SPOOL * HDIM;

    pool_rms_gelu_f32<<<SPOOL, 256, 0, stream>>>(x, w_rms, xn, xg);
    pos_enc_f32<<<PEROWS, 256, 0, stream>>>(W_pos, b_pos, pef);
    dim3 g1(HDTOT / BN, SPOOL / BM);
    gemm_f32<<<g1, 256, 0, stream>>>(xn, W_q, q, SPOOL, HDTOT, DMODEL);
    gemm_f32<<<g1, 256, 0, stream>>>(xn, W_k, k, SPOOL, HDTOT, DMODEL);
    dim3 g2(HDIM / BN, SPOOL / BM);
    gemm_f32<<<g2, 256, 0, stream>>>(xg, W_yq, yq, SPOOL, HDIM, DMODEL);
    gemm_f32<<<g2, 256, 0, stream>>>(xg, W_yk, yk, SPOOL, HDIM, DMODEL);
    dim3 g3(SPOOL / 256, SPOOL, NHEADS);
    score_kernel<<<g3, 256, 0, stream>>>(q, k, pef, qrb, krb, a);
    dim3 g4(SPOOL / 2, SPOOL);
    pair_kernel<<<g4, 256, 0, stream>>>(a, W_pair, b_pair, yq, yk, out);
  }
}

// Round 4
// 512.302 us; speedup vs baseline: 4.5283x; 1.4130x over previous
//
#include <hip/hip_runtime.h>
#include <hip/hip_bf16.h>
#include <math.h>
#include <stdint.h>

#define NHEADS 32
#define HDIM 128
#define POOLW 16
#define DMODEL 1536
#define SPOOL 512
#define HDTOT 4096   // NHEADS*HDIM
#define PEROWS 1024  // 2*SPOOL
#define NPAIR (SPOOL * SPOOL)   // 262144

typedef __hip_bfloat16 bf16;
typedef short short8 __attribute__((ext_vector_type(8)));
typedef float f32x4 __attribute__((ext_vector_type(4)));

__device__ __forceinline__ float b2f(const bf16 v) { return __bfloat162float(v); }
__device__ __forceinline__ bf16 f2b(float v) { return __float2bfloat16(v); }
__device__ __forceinline__ short f2bs(float v) {
  bf16 b = __float2bfloat16(v);
  return *reinterpret_cast<short*>(&b);
}

__device__ __forceinline__ void gload_lds16(const void* g, void* l) {
  const __attribute__((address_space(1))) uint32_t* gp =
      (const __attribute__((address_space(1))) uint32_t*)(uintptr_t)g;
  __attribute__((address_space(3))) uint32_t* lp =
      (__attribute__((address_space(3))) uint32_t*)(uintptr_t)l;
  __builtin_amdgcn_global_load_lds(gp, lp, 16, 0, 0);
}

// ---------------------------------------------------------------------------
// K1: pool (mean 16) + RMSNorm + GELU -> bf16 xn, xg
// ---------------------------------------------------------------------------
__global__ __launch_bounds__(256) void pool_rms_gelu_bf(
    const float* __restrict__ x, const float* __restrict__ w_rms,
    bf16* __restrict__ xn, bf16* __restrict__ xg) {
  int sp = blockIdx.x;
  int tid = threadIdx.x;
  __shared__ float buf[DMODEL];
  __shared__ float red[256];
  const float* xrow = x + (size_t)sp * POOLW * DMODEL;
  float ss = 0.f;
  for (int d = tid; d < DMODEL; d += 256) {
    float s = 0.f;
#pragma unroll
    for (int p = 0; p < POOLW; ++p) s += xrow[p * DMODEL + d];
    s *= (1.0f / POOLW);
    buf[d] = s;
    ss += s * s;
  }
  red[tid] = ss;
  __syncthreads();
  for (int off = 128; off > 0; off >>= 1) {
    if (tid < off) red[tid] += red[tid + off];
    __syncthreads();
  }
  float rms = rsqrtf(red[0] / DMODEL + 1e-6f);
  for (int d = tid; d < DMODEL; d += 256) {
    float v = buf[d] * rms * w_rms[d];
    xn[(size_t)sp * DMODEL + d] = f2b(v);
    xg[(size_t)sp * DMODEL + d] = f2b(0.5f * v * (1.0f + erff(v * 0.70710678118654752f)));
  }
}

// ---------------------------------------------------------------------------
// K2a: suffix sums of W_pos rows.  SW0[g][j] = sum_{f>=g} W_pos[f][j] (g=0..32)
//      SW1 likewise over rows 32..63. Row 32 is zero.
// ---------------------------------------------------------------------------
__global__ __launch_bounds__(256) void suffix_kernel(
    const float* __restrict__ W_pos, float* __restrict__ SW0, float* __restrict__ SW1) {
  int j = blockIdx.x * 256 + threadIdx.x;
  float s0 = 0.f, s1 = 0.f;
  SW0[32 * HDTOT + j] = 0.f;
  SW1[32 * HDTOT + j] = 0.f;
  for (int f = 31; f >= 0; --f) {
    s0 += W_pos[f * HDTOT + j];
    s1 += W_pos[(NHEADS + f) * HDTOT + j];
    SW0[f * HDTOT + j] = s0;
    SW1[f * HDTOT + j] = s1;
  }
}

// K2b: pe[p][j] = b_pos[j] + SW0[fmin][j] + sgn*SW1[fmin][j]
__global__ __launch_bounds__(256) void pos_enc2(
    const float* __restrict__ SW0, const float* __restrict__ SW1,
    const float* __restrict__ b_pos, bf16* __restrict__ pe) {
  int p = blockIdx.x;
  int rv = p - SPOOL;
  float dist = fabsf((float)rv);
  float sgn = (rv > 0) ? 1.f : ((rv < 0) ? -1.f : 0.f);
  // fmin = count of f with center_width(f) <= dist  (mask is a suffix since cw increasing)
  double ls = log(481.0) / 32.0;  // log(512-32+1)/32
  int fm = 0;
#pragma unroll
  for (int f = 0; f < 32; ++f) {
    float cw = (float)f + expf((float)f * (float)ls);
    if (cw <= dist) fm = f + 1;
  }
  const float* r0 = SW0 + (size_t)fm * HDTOT;
  const float* r1 = SW1 + (size_t)fm * HDTOT;
  for (int j = threadIdx.x; j < HDTOT; j += 256) {
    pe[(size_t)p * HDTOT + j] = f2b(b_pos[j] + r0[j] + sgn * r1[j]);
  }
}

// ---------------------------------------------------------------------------
// K3: transpose + cast  in[R][C] fp32 -> out[C][R] bf16
// ---------------------------------------------------------------------------
__global__ __launch_bounds__(256) void transpose_cast(
    const float* __restrict__ in, bf16* __restrict__ out, int R, int C) {
  __shared__ float tile[32][33];
  int c0 = blockIdx.x * 32, r0 = blockIdx.y * 32;
  int tx = threadIdx.x & 31, ty = threadIdx.x >> 5;  // ty 0..7
  for (int i = ty; i < 32; i += 8) tile[i][tx] = in[(size_t)(r0 + i) * C + c0 + tx];
  __syncthreads();
  for (int i = ty; i < 32; i += 8) out[(size_t)(c0 + i) * R + r0 + tx] = f2b(tile[tx][i]);
}

// ---------------------------------------------------------------------------
// K4: rank-1 bias corrections: cq[h][p] = qrb_h . pe_h[p], ck likewise.
// grid (32 h, 8 p-chunks), 256 threads (4 waves), each wave 32 p values.
// ---------------------------------------------------------------------------
__global__ __launch_bounds__(256) void cqck_kernel(
    const float* __restrict__ qrb, const float* __restrict__ krb,
    const bf16* __restrict__ pe, float* __restrict__ cq, float* __restrict__ ck) {
  int h = blockIdx.x, pc = blockIdx.y;
  int t = threadIdx.x, w = t >> 6, lane = t & 63;
  float q0 = qrb[h * HDIM + lane], q1 = qrb[h * HDIM + 64 + lane];
  float k0 = krb[h * HDIM + lane], k1 = krb[h * HDIM + 64 + lane];
  for (int i = 0; i < 32; ++i) {
    int p = pc * 128 + w * 32 + i;
    float e0 = b2f(pe[(size_t)p * HDTOT + h * HDIM + lane]);
    float e1 = b2f(pe[(size_t)p * HDTOT + h * HDIM + 64 + lane]);
    float sq = q0 * e0 + q1 * e1;
    float sk = k0 * e0 + k1 * e1;
#pragma unroll
    for (int off = 32; off > 0; off >>= 1) {
      sq += __shfl_xor(sq, off, 64);
      sk += __shfl_xor(sk, off, 64);
    }
    if (lane == 0) {
      cq[h * PEROWS + p] = sq;
      ck[h * PEROWS + p] = sk;
    }
  }
}

// ---------------------------------------------------------------------------
// K5: bf16 MFMA GEMM:  C[M][N] = A[M][K] @ BT[N][K]^T  (both K-contiguous)
// 128x64 tile, BK=32, 256 threads. Validated fragment conventions (round 3):
//   a_frag[j] = A[m=lane&15][k=quad*8+j]; b_frag same on BT; D row=quad*4+r, col=lane&15.
// mode 0: fp32 store; mode 1: bf16 store;
// mode 2: diagonal remap + in-place RMW into SD[h][gm][kk=gn-512+gm]:
//         SD += 0.5*(v + extra[h][gn])   (only kk in [0,512))
// ---------------------------------------------------------------------------
__global__ __launch_bounds__(256) void gemm_mfma(
    const bf16* __restrict__ A, int lda, long long batchA,
    const bf16* __restrict__ BT, int ldb, long long batchB,
    void* __restrict__ C, int ldc, long long batchC,
    const float* __restrict__ extra, int mode, int M, int N, int K) {
  __shared__ short Asub[128][32];
  __shared__ short Bsub[64][32];
  const int t = threadIdx.x;
  const int lane = t & 63;
  const int w = t >> 6;
  const int m0 = blockIdx.y * 128, n0 = blockIdx.x * 64;
  const int wm = (w >> 1) * 64, wn = (w & 1) * 32;
  const bf16* Ag = A + (size_t)blockIdx.z * batchA;
  const bf16* Bg = BT + (size_t)blockIdx.z * batchB;

  const int ar0 = t >> 2;
  const int as0 = t & 3;
  const int ao0 = as0 ^ (ar0 & 3);
  char* AsubB = (char*)&Asub[0][0];
  char* BsubB = (char*)&Bsub[0][0];
  char* ldsA0 = AsubB + w * 1024;
  char* ldsA1 = AsubB + 4096 + w * 1024;
  char* ldsB0 = BsubB + w * 1024;

  const int quad = lane >> 4, mr = lane & 15;
  f32x4 acc[4][2];
#pragma unroll
  for (int mi = 0; mi < 4; ++mi)
#pragma unroll
    for (int ni = 0; ni < 2; ++ni) acc[mi][ni] = (f32x4){0.f, 0.f, 0.f, 0.f};

  for (int k0 = 0; k0 < K; k0 += 32) {
    gload_lds16(Ag + (size_t)(m0 + ar0) * lda + k0 + ao0 * 8, ldsA0);
    gload_lds16(Ag + (size_t)(m0 + 64 + ar0) * lda + k0 + ao0 * 8, ldsA1);
    gload_lds16(Bg + (size_t)(n0 + ar0) * ldb + k0 + ao0 * 8, ldsB0);
    __syncthreads();
    short8 af[4];
#pragma unroll
    for (int mi = 0; mi < 4; ++mi) {
      int r = wm + mi * 16 + mr;
      af[mi] = *(const short8*)&Asub[r][(quad ^ (r & 3)) * 8];
    }
    short8 bfr[2];
#pragma unroll
    for (int ni = 0; ni < 2; ++ni) {
      int r = wn + ni * 16 + mr;
      bfr[ni] = *(const short8*)&Bsub[r][(quad ^ (r & 3)) * 8];
    }
#pragma unroll
    for (int mi = 0; mi < 4; ++mi)
#pragma unroll
      for (int ni = 0; ni < 2; ++ni)
        acc[mi][ni] = __builtin_amdgcn_mfma_f32_16x16x32_bf16(af[mi], bfr[ni], acc[mi][ni], 0, 0, 0);
    __syncthreads();
  }

  size_t cbase = (size_t)blockIdx.z * batchC;
#pragma unroll
  for (int mi = 0; mi < 4; ++mi) {
#pragma unroll
    for (int ni = 0; ni < 2; ++ni) {
#pragma unroll
      for (int r = 0; r < 4; ++r) {
        int gm = m0 + wm + mi * 16 + quad * 4 + r;
        int gn = n0 + wn + ni * 16 + mr;
        float v = acc[mi][ni][r];
        if (mode == 0) {
          ((float*)C)[cbase + (size_t)gm * ldc + gn] = v;
        } else if (mode == 1) {
          ((bf16*)C)[cbase + (size_t)gm * ldc + gn] = f2b(v);
        } else {
          int kk = gn - 512 + gm;
          if (kk >= 0 && kk < 512) {
            bf16* Cb = (bf16*)C;
            size_t idx = (size_t)blockIdx.z * NPAIR + (size_t)gm * 512 + kk;
            float corr = extra[blockIdx.z * PEROWS + gn];
            Cb[idx] = f2b(b2f(Cb[idx]) + 0.5f * (v + corr));
          }
        }
      }
    }
  }
}

// ---------------------------------------------------------------------------
// K6: combine -> P[(q*512+k)][h] (bf16, h contiguous)
// P = SD[h][q][k] + 0.5*(Gk[h][k][512+q-k] + ck[h][512+q-k])
// grid (512 q, 2), 256 threads, thread owns one k.
// ---------------------------------------------------------------------------
__global__ __launch_bounds__(256) void combine_kernel(
    const bf16* __restrict__ SD, const bf16* __restrict__ Gk,
    const float* __restrict__ ck, bf16* __restrict__ P) {
  int q = blockIdx.x;
  int k = blockIdx.y * 256 + threadIdx.x;
  int p = 512 + q - k;
  bf16* Pout = P + ((size_t)q * 512 + k) * 32;
#pragma unroll
  for (int h8 = 0; h8 < 4; ++h8) {
    short8 pack;
#pragma unroll
    for (int j = 0; j < 8; ++j) {
      int h = h8 * 8 + j;
      float sd = b2f(SD[((size_t)(h * 512 + q)) * 512 + k]);
      float gk = b2f(Gk[((size_t)(h * 512 + k)) * PEROWS + p]);
      float cc = ck[h * PEROWS + p];
      pack[j] = f2bs(sd + 0.5f * (gk + cc));
    }
    *(short8*)(Pout + h8 * 8) = pack;
  }
}

// ---------------------------------------------------------------------------
// K7: pair projection MFMA:  out[m][c] = P[m][:32] @ W_pair[:32][c] + b_pair[c]
//                                        + yqk[q][c] + yqk[k][128+c]
// M = 262144 (qk), N = 128 (c), K = 32 (h). Block: m-tile 128, 4 waves (32 m each).
// A-frags loaded directly from P (16B aligned); B from W_pairT [128][32].
// ---------------------------------------------------------------------------
__global__ __launch_bounds__(256) void pair_gemm(
    const bf16* __restrict__ P, const bf16* __restrict__ WpT,
    const float* __restrict__ b_pair, const float* __restrict__ yqk,
    float* __restrict__ out) {
  int t = threadIdx.x, lane = t & 63, w = t >> 6;
  int quad = lane >> 4, mr = lane & 15;
  int m0 = blockIdx.x * 128;
  int wm = w * 32;
  int q = m0 >> 9;  // constant per block (128 | 512)

  short8 af[2];
#pragma unroll
  for (int mi = 0; mi < 2; ++mi) {
    int m = m0 + wm + mi * 16 + mr;
    af[mi] = *(const short8*)(P + (size_t)m * 32 + quad * 8);
  }

  f32x4 acc[2][8];
#pragma unroll
  for (int mi = 0; mi < 2; ++mi)
#pragma unroll
    for (int ni = 0; ni < 8; ++ni) acc[mi][ni] = (f32x4){0.f, 0.f, 0.f, 0.f};

  float bqv[8];
#pragma unroll
  for (int ni = 0; ni < 8; ++ni) {
    int c = ni * 16 + mr;
    bqv[ni] = b_pair[c] + yqk[(size_t)q * 256 + c];
    short8 bfr = *(const short8*)(WpT + (size_t)c * 32 + quad * 8);
#pragma unroll
    for (int mi = 0; mi < 2; ++mi)
      acc[mi][ni] = __builtin_amdgcn_mfma_f32_16x16x32_bf16(af[mi], bfr, acc[mi][ni], 0, 0, 0);
  }

#pragma unroll
  for (int mi = 0; mi < 2; ++mi) {
#pragma unroll
    for (int r = 0; r < 4; ++r) {
      int m_out = m0 + wm + mi * 16 + quad * 4 + r;
      int k = m_out & 511;
      const float* ykrow = yqk + (size_t)k * 256 + 128;
#pragma unroll
      for (int ni = 0; ni < 8; ++ni) {
        int c = ni * 16 + mr;
        out[(size_t)m_out * HDIM + c] = acc[mi][ni][r] + bqv[ni] + ykrow[c];
      }
    }
  }
}

// ===========================================================================
extern "C" void kernel_launch(void* const* d_in, const int* in_sizes, int n_in,
                              void* d_out, int out_size, void* d_ws, size_t ws_size,
                              hipStream_t stream) {
  const float* x      = (const float*)d_in[0];
  const float* w_rms  = (const float*)d_in[1];
  const float* W_q    = (const float*)d_in[2];
  const float* W_k    = (const float*)d_in[3];
  const float* W_pos  = (const float*)d_in[4];
  const float* b_pos  = (const float*)d_in[5];
  const float* qrb    = (const float*)d_in[6];
  const float* krb    = (const float*)d_in[7];
  const float* W_yq   = (const float*)d_in[8];
  const float* W_yk   = (const float*)d_in[9];
  const float* W_pair = (const float*)d_in[10];
  const float* b_pair = (const float*)d_in[11];
  float* out = (float*)d_out;

  // ---- workspace layout (~90 MB) ----
  char* w = (char*)d_ws;
  bf16* xn   = (bf16*)w; w += (size_t)SPOOL * DMODEL * 2;       // 1.5 MB
  bf16* xg   = (bf16*)w; w += (size_t)SPOOL * DMODEL * 2;       // 1.5 MB
  bf16* pe   = (bf16*)w; w += (size_t)PEROWS * HDTOT * 2;       // 8.4 MB
  bf16* Qp   = (bf16*)w; w += (size_t)SPOOL * HDTOT * 2;        // 4.2 MB
  bf16* Kp   = (bf16*)w; w += (size_t)SPOOL * HDTOT * 2;        // 4.2 MB
  float* yqk = (float*)w; w += (size_t)SPOOL * 256 * 4;         // 0.5 MB
  bf16* yqkT = (bf16*)w; w += (size_t)256 * DMODEL * 2;         // 0.8 MB
  bf16* WpT  = (bf16*)w; w += (size_t)HDIM * NHEADS * 2;        // 8 KB
  float* SW0 = (float*)w; w += (size_t)33 * HDTOT * 4;          // 0.54 MB
  float* SW1 = (float*)w; w += (size_t)33 * HDTOT * 4;          // 0.54 MB
  float* cq  = (float*)w; w += (size_t)NHEADS * PEROWS * 4;     // 0.13 MB
  float* ck  = (float*)w; w += (size_t)NHEADS * PEROWS * 4;     // 0.13 MB
  // union region: {WqT, WkT} live only until projections; Gk written after.
  char* uni = w;
  bf16* WqT = (bf16*)uni;
  bf16* WkT = (bf16*)(uni + (size_t)HDTOT * DMODEL * 2);        // 12.6 MB each
  bf16* Gk  = (bf16*)uni;                                       // 33.6 MB
  w = uni + (size_t)NHEADS * SPOOL * PEROWS * 2;
  bf16* SD  = (bf16*)w; w += (size_t)NHEADS * NPAIR * 2;        // 16.8 MB
  bf16* P   = (bf16*)w; w += (size_t)NPAIR * NHEADS * 2;        // 16.8 MB

  // 1. pool + rms + gelu
  pool_rms_gelu_bf<<<SPOOL, 256, 0, stream>>>(x, w_rms, xn, xg);
  // 2. pos-enc via suffix sums
  suffix_kernel<<<HDTOT / 256, 256, 0, stream>>>(W_pos, SW0, SW1);
  pos_enc2<<<PEROWS, 256, 0, stream>>>(SW0, SW1, b_pos, pe);
  // 3. weight transposes (bf16, K-contiguous)
  transpose_cast<<<dim3(HDTOT / 32, DMODEL / 32), 256, 0, stream>>>(W_q, WqT, DMODEL, HDTOT);
  transpose_cast<<<dim3(HDTOT / 32, DMODEL / 32), 256, 0, stream>>>(W_k, WkT, DMODEL, HDTOT);
  transpose_cast<<<dim3(HDIM / 32, DMODEL / 32), 256, 0, stream>>>(W_yq, yqkT, DMODEL, HDIM);
  transpose_cast<<<dim3(HDIM / 32, DMODEL / 32), 256, 0, stream>>>(W_yk, yqkT + (size_t)HDIM * DMODEL, DMODEL, HDIM);
  transpose_cast<<<dim3(HDIM / 32, 1), 256, 0, stream>>>(W_pair, WpT, NHEADS, HDIM);
  // 4. rank-1 bias corrections
  cqck_kernel<<<dim3(NHEADS, 8), 256, 0, stream>>>(qrb, krb, pe, cq, ck);
  // 5. projections (bf16 out)
  gemm_mfma<<<dim3(HDTOT / 64, SPOOL / 128, 1), 256, 0, stream>>>(
      xn, DMODEL, 0, WqT, DMODEL, 0, Qp, HDTOT, 0, nullptr, 1, SPOOL, HDTOT, DMODEL);
  gemm_mfma<<<dim3(HDTOT / 64, SPOOL / 128, 1), 256, 0, stream>>>(
      xn, DMODEL, 0, WkT, DMODEL, 0, Kp, HDTOT, 0, nullptr, 1, SPOOL, HDTOT, DMODEL);
  // 6. yq|yk (fp32 out)
  gemm_mfma<<<dim3(256 / 64, SPOOL / 128, 1), 256, 0, stream>>>(
      xg, DMODEL, 0, yqkT, DMODEL, 0, yqk, 256, 0, nullptr, 0, SPOOL, 256, DMODEL);
  // 7. S[h][q][k] = Q_h . K_h^T  (bf16)
  gemm_mfma<<<dim3(SPOOL / 64, SPOOL / 128, NHEADS), 256, 0, stream>>>(
      Qp, HDTOT, HDIM, Kp, HDTOT, HDIM, SD, 512, NPAIR, nullptr, 1, SPOOL, SPOOL, HDIM);
  // 8. Dq: SD[h][q][k=p-512+q] += 0.5*(Q.pe^T + cq)  (diagonal remap, in-place RMW)
  gemm_mfma<<<dim3(PEROWS / 64, SPOOL / 128, NHEADS), 256, 0, stream>>>(
      Qp, HDTOT, HDIM, pe, HDTOT, HDIM, SD, 512, NPAIR, cq, 2, SPOOL, PEROWS, HDIM);
  // 9. Gk[h][k][p] = K_h . pe_h^T  (full, bf16)
  gemm_mfma<<<dim3(PEROWS / 64, SPOOL / 128, NHEADS), 256, 0, stream>>>(
      Kp, HDTOT, HDIM, pe, HDTOT, HDIM, Gk, PEROWS, (long long)SPOOL * PEROWS, nullptr, 1,
      SPOOL, PEROWS, HDIM);
  // 10. combine -> P[(qk)][h]
  combine_kernel<<<dim3(SPOOL, 2), 256, 0, stream>>>(SD, Gk, ck, P);
  // 11. pair projection + epilogue
  pair_gemm<<<NPAIR / 128, 256, 0, stream>>>(P, WpT, b_pair, yqk, out);
}